// Round 1
// baseline (80.346 us; speedup 1.0000x reference)
//
#include <hip/hip_runtime.h>

// MultiLinear: out[i] = inputs[i] @ w[indices[i]] + b[indices[i]]
// B=16384, OPT=64, IN=128, OUT=128, fp32 in/out, int32 indices.
//
// Strategy: grid = (64 options x 8 slices). Each block:
//   1. scans its 2048-example slice for indices[i]==option, compacts into LDS list
//   2. holds w[option] as bf16 MFMA B-fragments in registers (loaded once)
//   3. processes matched rows in 16-row M-tiles with mfma_f32_16x16x32_bf16
// Weight reuse lives in registers; only the small match-list touches LDS.

#define B_TOT    16384
#define NOPT     64
#define DIN      128
#define DOUT     128
#define NSLICE   8
#define SLICE_LEN (B_TOT / NSLICE)   // 2048
#define NTHREADS 256

typedef __attribute__((ext_vector_type(8))) short  short8;
typedef __attribute__((ext_vector_type(4))) float  floatx4;

static __device__ __forceinline__ short f2bf(float f) {
    // round-to-nearest-even fp32 -> bf16 (inputs are finite normals; no NaN path)
    union { float f; unsigned u; } v; v.f = f;
    unsigned r = v.u + 0x7fffu + ((v.u >> 16) & 1u);
    return (short)(r >> 16);
}

__global__ __launch_bounds__(NTHREADS)
void multilinear_kernel(const float* __restrict__ x,
                        const float* __restrict__ w,
                        const float* __restrict__ bias,
                        const int*   __restrict__ idx,
                        float* __restrict__ out) {
    __shared__ int s_list[SLICE_LEN];
    __shared__ int s_cnt;

    const int bid = blockIdx.x;
    const int o   = bid >> 3;            // option [0,64)
    const int s   = bid & (NSLICE - 1);  // slice  [0,8)
    const int t   = threadIdx.x;

    if (t == 0) s_cnt = 0;
    __syncthreads();

    // --- phase 1: compact matching example ids into LDS (order irrelevant) ---
    const int base = s * SLICE_LEN;
    #pragma unroll
    for (int k = 0; k < SLICE_LEN / NTHREADS; ++k) {
        int i = base + t + k * NTHREADS;
        if (idx[i] == o) {
            int p = atomicAdd(&s_cnt, 1);
            s_list[p] = i;
        }
    }
    __syncthreads();
    const int count = s_cnt;
    if (count == 0) return;

    const int wave = t >> 6;     // 0..3 -> n-tiles {2*wave, 2*wave+1}
    const int lane = t & 63;
    const int l15  = lane & 15;
    const int quad = lane >> 4;  // 0..3

    // --- phase 2: load B fragments (w[o]) into registers, fp32 -> bf16 ---
    // B[k][n]: lane holds k = kb*32 + quad*8 + j, n = ntile*16 + l15
    const float* wo = w + (size_t)o * DIN * DOUT;
    short8 bfrag[4][2];
    #pragma unroll
    for (int kb = 0; kb < 4; ++kb) {
        #pragma unroll
        for (int nt = 0; nt < 2; ++nt) {
            const int n  = (wave * 2 + nt) * 16 + l15;
            const int k0 = kb * 32 + quad * 8;
            short8 f;
            #pragma unroll
            for (int j = 0; j < 8; ++j)
                f[j] = f2bf(wo[(size_t)(k0 + j) * DOUT + n]);
            bfrag[kb][nt] = f;
        }
    }

    float bv[2];
    #pragma unroll
    for (int nt = 0; nt < 2; ++nt)
        bv[nt] = bias[o * DOUT + (wave * 2 + nt) * 16 + l15];

    // --- phase 3: M-tiles of 16 matched rows ---
    const int mtiles = (count + 15) >> 4;
    for (int mt = 0; mt < mtiles; ++mt) {
        // A fragment row for this lane (clamped for ragged tail; stores guarded)
        int am = mt * 16 + l15;
        int arid = s_list[am < count ? am : count - 1];
        const float* xr = x + (size_t)arid * DIN;

        floatx4 acc[2] = {{0.f,0.f,0.f,0.f},{0.f,0.f,0.f,0.f}};
        #pragma unroll
        for (int kb = 0; kb < 4; ++kb) {
            const int k0 = kb * 32 + quad * 8;   // %8==0 -> 32B-aligned float4 pairs
            float4 xa = *(const float4*)(xr + k0);
            float4 xb = *(const float4*)(xr + k0 + 4);
            short8 af;
            af[0] = f2bf(xa.x); af[1] = f2bf(xa.y);
            af[2] = f2bf(xa.z); af[3] = f2bf(xa.w);
            af[4] = f2bf(xb.x); af[5] = f2bf(xb.y);
            af[6] = f2bf(xb.z); af[7] = f2bf(xb.w);
            acc[0] = __builtin_amdgcn_mfma_f32_16x16x32_bf16(af, bfrag[kb][0], acc[0], 0, 0, 0);
            acc[1] = __builtin_amdgcn_mfma_f32_16x16x32_bf16(af, bfrag[kb][1], acc[1], 0, 0, 0);
        }

        // C/D layout: col = l15, row = quad*4 + r
        #pragma unroll
        for (int r = 0; r < 4; ++r) {
            const int m = mt * 16 + quad * 4 + r;
            if (m < count) {
                const int rid = s_list[m];
                #pragma unroll
                for (int nt = 0; nt < 2; ++nt) {
                    const int n = (wave * 2 + nt) * 16 + l15;
                    out[(size_t)rid * DOUT + n] = acc[nt][r] + bv[nt];
                }
            }
        }
    }
}

extern "C" void kernel_launch(void* const* d_in, const int* in_sizes, int n_in,
                              void* d_out, int out_size, void* d_ws, size_t ws_size,
                              hipStream_t stream) {
    const float* x    = (const float*)d_in[0];  // [16384,128]
    const float* w    = (const float*)d_in[1];  // [64,128,128]
    const float* bias = (const float*)d_in[2];  // [64,128]
    const int*   idx  = (const int*)d_in[3];    // [16384]
    float* out        = (float*)d_out;          // [16384,128]

    multilinear_kernel<<<NOPT * NSLICE, NTHREADS, 0, stream>>>(x, w, bias, idx, out);
}

// Round 2
// 76.431 us; speedup vs baseline: 1.0512x; 1.0512x over previous
//
#include <hip/hip_runtime.h>

// MultiLinear: out[i] = inputs[i] @ w[indices[i]] + b[indices[i]]
// B=16384, OPT=64, IN=128, OUT=128, fp32 in/out, int32 indices.
//
// v2: two-kernel pipeline.
//  k1: w [64][128k][128n] fp32  ->  wT [64][128n][128k] bf16 in d_ws.
//      One-time convert+transpose so MFMA B-fragments (k-contiguous) can be
//      loaded with wide vector ops instead of 64 scalar strided loads.
//  k2: grid = 64 options x 16 slices. Each block:
//      - compacts matching row ids from its 1024-idx slice into LDS
//      - stages wT[o] (32 KB bf16) into LDS, row-padded +8 bf16 so frag
//        ds_read_b128 is ~conflict-free
//      - 16-row M-tiles: A gathered from x (fp32->bf16 inline),
//        mfma_f32_16x16x32_bf16, fused bias, store.

#define B_TOT     16384
#define NOPT      64
#define DIN       128
#define DOUT      128
#define NSLICE    16
#define SLICE_LEN (B_TOT / NSLICE)   // 1024
#define NTHREADS  256
#define SP        136                // padded LDS row stride (bf16 elems); 136*2=272B

typedef __attribute__((ext_vector_type(8))) short  short8;
typedef __attribute__((ext_vector_type(4))) float  floatx4;

static __device__ __forceinline__ short f2bf(float f) {
    // round-to-nearest-even fp32 -> bf16
    union { float f; unsigned u; } v; v.f = f;
    unsigned r = v.u + 0x7fffu + ((v.u >> 16) & 1u);
    return (short)(r >> 16);
}

// k1: wT[o][n][k] = bf16(w[o][k][n]).  Grid: 256 blocks (64 options x 4 n-parts).
__global__ __launch_bounds__(NTHREADS)
void convert_wT_kernel(const float* __restrict__ w, unsigned short* __restrict__ wT) {
    const int o = blockIdx.x & 63;
    const int p = blockIdx.x >> 6;        // n-part 0..3
    const int t = threadIdx.x;
    const int nn = p * 32 + (t & 31);     // output row (n)
    const float* wo = w + (size_t)o * DIN * DOUT;
    unsigned short* wto = wT + (size_t)o * DIN * DOUT;
    #pragma unroll
    for (int it = 0; it < 2; ++it) {
        const int c = (t >> 5) + 8 * it;  // k-chunk 0..15
        short8 v;
        #pragma unroll
        for (int j = 0; j < 8; ++j)
            v[j] = f2bf(wo[(size_t)(c * 8 + j) * DOUT + nn]);  // coalesced across lanes (nn)
        *(short8*)(wto + (size_t)nn * DIN + c * 8) = v;        // 16B store
    }
}

__global__ __launch_bounds__(NTHREADS)
void multilinear_kernel(const float* __restrict__ x,
                        const unsigned short* __restrict__ wT,
                        const float* __restrict__ bias,
                        const int*   __restrict__ idx,
                        float* __restrict__ out) {
    __shared__ int s_list[SLICE_LEN];
    __shared__ int s_cnt;
    __shared__ unsigned short s_w[DOUT * SP];   // wT[o] padded: 34816 B

    const int bid = blockIdx.x;
    const int o   = bid & 63;             // option
    const int s   = bid >> 6;             // slice 0..15
    const int t   = threadIdx.x;

    if (t == 0) s_cnt = 0;
    __syncthreads();

    // --- scan slice for matching rows (order irrelevant) ---
    const int base = s * SLICE_LEN;
    #pragma unroll
    for (int k = 0; k < SLICE_LEN / NTHREADS; ++k) {
        int i = base + t + k * NTHREADS;
        if (idx[i] == o) {
            int p = atomicAdd(&s_cnt, 1);
            s_list[p] = i;
        }
    }

    // --- stage wT[o] into LDS (coalesced 16B loads, padded rows) ---
    const unsigned short* wto = wT + (size_t)o * DIN * DOUT;
    #pragma unroll
    for (int it = 0; it < 8; ++it) {
        const int e16 = it * NTHREADS + t;   // 16B-chunk id, 0..2047
        const int n   = e16 >> 4;            // row (n), 0..127
        const int c   = e16 & 15;            // chunk within row
        short8 v = *(const short8*)(wto + (size_t)n * DIN + c * 8);
        *(short8*)(&s_w[n * SP + c * 8]) = v;
    }
    __syncthreads();

    const int count = s_cnt;
    if (count == 0) return;

    const int wave = t >> 6;     // 0..3 -> n-tiles {2w, 2w+1}
    const int lane = t & 63;
    const int l15  = lane & 15;
    const int quad = lane >> 4;  // 0..3

    const int n0 = (wave * 2 + 0) * 16 + l15;
    const int n1 = (wave * 2 + 1) * 16 + l15;
    const float bv0 = bias[o * DOUT + n0];
    const float bv1 = bias[o * DOUT + n1];

    // --- 16-row M-tiles over matched rows ---
    const int mtiles = (count + 15) >> 4;
    for (int mt = 0; mt < mtiles; ++mt) {
        int am = mt * 16 + l15;
        int arid = s_list[am < count ? am : count - 1];
        const float* xr = x + (size_t)arid * DIN;

        floatx4 acc0 = {0.f, 0.f, 0.f, 0.f};
        floatx4 acc1 = {0.f, 0.f, 0.f, 0.f};
        #pragma unroll
        for (int kb = 0; kb < 4; ++kb) {
            const int k0 = kb * 32 + quad * 8;       // 32B-aligned
            float4 xa = *(const float4*)(xr + k0);
            float4 xb = *(const float4*)(xr + k0 + 4);
            short8 af;
            af[0] = f2bf(xa.x); af[1] = f2bf(xa.y);
            af[2] = f2bf(xa.z); af[3] = f2bf(xa.w);
            af[4] = f2bf(xb.x); af[5] = f2bf(xb.y);
            af[6] = f2bf(xb.z); af[7] = f2bf(xb.w);
            short8 b0 = *(const short8*)(&s_w[n0 * SP + k0]);  // ds_read_b128
            short8 b1 = *(const short8*)(&s_w[n1 * SP + k0]);
            acc0 = __builtin_amdgcn_mfma_f32_16x16x32_bf16(af, b0, acc0, 0, 0, 0);
            acc1 = __builtin_amdgcn_mfma_f32_16x16x32_bf16(af, b1, acc1, 0, 0, 0);
        }

        // C/D: col = l15, row = quad*4 + r
        #pragma unroll
        for (int r = 0; r < 4; ++r) {
            const int m = mt * 16 + quad * 4 + r;
            if (m < count) {
                const int rid = s_list[m];
                out[(size_t)rid * DOUT + n0] = acc0[r] + bv0;
                out[(size_t)rid * DOUT + n1] = acc1[r] + bv1;
            }
        }
    }
}

extern "C" void kernel_launch(void* const* d_in, const int* in_sizes, int n_in,
                              void* d_out, int out_size, void* d_ws, size_t ws_size,
                              hipStream_t stream) {
    const float* x    = (const float*)d_in[0];  // [16384,128]
    const float* w    = (const float*)d_in[1];  // [64,128,128]
    const float* bias = (const float*)d_in[2];  // [64,128]
    const int*   idx  = (const int*)d_in[3];    // [16384]
    float* out        = (float*)d_out;          // [16384,128]
    unsigned short* wT = (unsigned short*)d_ws; // [64,128,128] bf16, 2 MB

    convert_wT_kernel<<<NOPT * 4, NTHREADS, 0, stream>>>(w, wT);
    multilinear_kernel<<<NOPT * NSLICE, NTHREADS, 0, stream>>>(x, wT, bias, idx, out);
}

// Round 3
// 74.771 us; speedup vs baseline: 1.0746x; 1.0222x over previous
//
#include <hip/hip_runtime.h>

// MultiLinear: out[i] = inputs[i] @ w[indices[i]] + b[indices[i]]
// B=16384, OPT=64, IN=128, OUT=128, fp32 in/out, int32 indices.
//
// v3: single fused kernel (the separate w-transpose dispatch in v2 was
// latency-bound serialized overhead; rocprof showed dur_us is dominated by
// harness reset fills, so the win is minimizing our own critical path).
// Grid = 64 options x 8 slices. Each block:
//   - stages w[o] natural-layout [k][n] into LDS as bf16 (coalesced float4
//     reads + inline cvt; SPN=132 padding). Issued before the idx scan so
//     both latencies overlap; ONE barrier.
//   - compacts matching row ids (ushort) from its 2048-idx slice
//   - builds MFMA B-fragments once per block from LDS (64 scalar ds_reads,
//     one-time, ~4-way conflicts = acceptable)
//   - 16-row M-tiles: A gathered from x (fp32->bf16 inline),
//     mfma_f32_16x16x32_bf16, fused bias, store.

#define B_TOT     16384
#define NOPT      64
#define DIN       128
#define DOUT      128
#define NSLICE    8
#define SLICE_LEN (B_TOT / NSLICE)   // 2048
#define NTHREADS  256
#define SPN       132                // LDS row stride (bf16 elems); 264 B, 8B-aligned rows

typedef __attribute__((ext_vector_type(8))) short  short8;
typedef __attribute__((ext_vector_type(4))) float  floatx4;

static __device__ __forceinline__ short f2bf(float f) {
    // round-to-nearest-even fp32 -> bf16 (finite normals; no NaN path)
    union { float f; unsigned u; } v; v.f = f;
    unsigned r = v.u + 0x7fffu + ((v.u >> 16) & 1u);
    return (short)(r >> 16);
}

__global__ __launch_bounds__(NTHREADS, 4)
void multilinear_kernel(const float* __restrict__ x,
                        const float* __restrict__ w,
                        const float* __restrict__ bias,
                        const int*   __restrict__ idx,
                        float* __restrict__ out) {
    __shared__ __align__(16) unsigned short s_w[DIN * SPN];  // 33792 B
    __shared__ unsigned short s_list[SLICE_LEN];             // 4096 B
    __shared__ int s_cnt;

    const int o = blockIdx.x & (NOPT - 1);   // option
    const int s = blockIdx.x >> 6;           // slice 0..7
    const int t = threadIdx.x;

    if (t == 0) s_cnt = 0;
    __syncthreads();

    // --- stage w[o] (fp32, natural [k][n]) -> LDS bf16, coalesced float4 ---
    const float* wo = w + (size_t)o * (DIN * DOUT);
    #pragma unroll
    for (int it = 0; it < 16; ++it) {
        const int e = it * NTHREADS + t;      // 16B-chunk id, 0..4095
        const int k = e >> 5;                 // row (k)
        const int c = e & 31;                 // float4-chunk within row
        float4 v = ((const float4*)wo)[e];
        ushort4 h;
        h.x = (unsigned short)f2bf(v.x); h.y = (unsigned short)f2bf(v.y);
        h.z = (unsigned short)f2bf(v.z); h.w = (unsigned short)f2bf(v.w);
        *(ushort4*)(&s_w[k * SPN + c * 4]) = h;   // 8 B, aligned (264k+8c)
    }

    // --- scan slice for matching rows (int4 loads, order irrelevant) ---
    const int base = s * SLICE_LEN;
    const int4* ip = (const int4*)(idx + base);
    #pragma unroll
    for (int it = 0; it < SLICE_LEN / (4 * NTHREADS); ++it) {
        const int e = it * NTHREADS + t;
        int4 v = ip[e];
        const int i0 = base + e * 4;
        if (v.x == o) s_list[atomicAdd(&s_cnt, 1)] = (unsigned short)(i0 + 0);
        if (v.y == o) s_list[atomicAdd(&s_cnt, 1)] = (unsigned short)(i0 + 1);
        if (v.z == o) s_list[atomicAdd(&s_cnt, 1)] = (unsigned short)(i0 + 2);
        if (v.w == o) s_list[atomicAdd(&s_cnt, 1)] = (unsigned short)(i0 + 3);
    }
    __syncthreads();

    const int count = s_cnt;
    if (count == 0) return;

    const int wave = t >> 6;     // 0..3 -> n-tiles {2w, 2w+1}
    const int lane = t & 63;
    const int l15  = lane & 15;
    const int quad = lane >> 4;  // 0..3

    const int n0 = (wave * 2) * 16 + l15;
    const int n1 = n0 + 16;

    // --- build B fragments once per block (one-time scalar LDS reads) ---
    // B[k][n]: lane holds k = kb*32 + quad*8 + j, n fixed per ntile
    short8 bf[4][2];
    #pragma unroll
    for (int kb = 0; kb < 4; ++kb) {
        #pragma unroll
        for (int j = 0; j < 8; ++j) {
            const int k = kb * 32 + quad * 8 + j;
            bf[kb][0][j] = (short)s_w[k * SPN + n0];
            bf[kb][1][j] = (short)s_w[k * SPN + n1];
        }
    }

    const float bv0 = bias[o * DOUT + n0];
    const float bv1 = bias[o * DOUT + n1];

    // --- 16-row M-tiles over matched rows ---
    const int mtiles = (count + 15) >> 4;
    for (int mt = 0; mt < mtiles; ++mt) {
        const int am = mt * 16 + l15;
        const int arid = s_list[am < count ? am : count - 1];
        const float* xr = x + (size_t)arid * DIN;

        floatx4 acc0 = {0.f, 0.f, 0.f, 0.f};
        floatx4 acc1 = {0.f, 0.f, 0.f, 0.f};
        #pragma unroll
        for (int kb = 0; kb < 4; ++kb) {
            const int k0 = kb * 32 + quad * 8;       // 32B-aligned
            float4 xa = *(const float4*)(xr + k0);
            float4 xb = *(const float4*)(xr + k0 + 4);
            short8 af;
            af[0] = f2bf(xa.x); af[1] = f2bf(xa.y);
            af[2] = f2bf(xa.z); af[3] = f2bf(xa.w);
            af[4] = f2bf(xb.x); af[5] = f2bf(xb.y);
            af[6] = f2bf(xb.z); af[7] = f2bf(xb.w);
            acc0 = __builtin_amdgcn_mfma_f32_16x16x32_bf16(af, bf[kb][0], acc0, 0, 0, 0);
            acc1 = __builtin_amdgcn_mfma_f32_16x16x32_bf16(af, bf[kb][1], acc1, 0, 0, 0);
        }

        // C/D: col = l15, row = quad*4 + r
        #pragma unroll
        for (int r = 0; r < 4; ++r) {
            const int m = mt * 16 + quad * 4 + r;
            if (m < count) {
                const int rid = s_list[m];
                out[(size_t)rid * DOUT + n0] = acc0[r] + bv0;
                out[(size_t)rid * DOUT + n1] = acc1[r] + bv1;
            }
        }
    }
}

extern "C" void kernel_launch(void* const* d_in, const int* in_sizes, int n_in,
                              void* d_out, int out_size, void* d_ws, size_t ws_size,
                              hipStream_t stream) {
    const float* x    = (const float*)d_in[0];  // [16384,128]
    const float* w    = (const float*)d_in[1];  // [64,128,128]
    const float* bias = (const float*)d_in[2];  // [64,128]
    const int*   idx  = (const int*)d_in[3];    // [16384]
    float* out        = (float*)d_out;          // [16384,128]

    multilinear_kernel<<<NOPT * NSLICE, NTHREADS, 0, stream>>>(x, w, bias, idx, out);
}